// Round 5
// baseline (622.160 us; speedup 1.0000x reference)
//
#include <hip/hip_runtime.h>

typedef unsigned short u16;
typedef float  f32x4 __attribute__((ext_vector_type(4)));
typedef short  s16x8 __attribute__((ext_vector_type(8)));
typedef unsigned short u16x4 __attribute__((ext_vector_type(4)));

#define NT 4194304   // 16384*256 token-matrix elements

__device__ __forceinline__ u16 f2b(float f) {
    unsigned b = __float_as_uint(f);
    return (u16)((b + 0x7FFFu + ((b >> 16) & 1u)) >> 16);   // RNE
}
__device__ __forceinline__ float b2f(u16 u) { return __uint_as_float(((unsigned)u) << 16); }

// pack 8 consecutive fp32 -> bf16x8 fragment
__device__ __forceinline__ s16x8 pack8(const float* p) {
    f32x4 lo = *(const f32x4*)p, hi = *(const f32x4*)(p + 4);
    union { s16x8 v; u16 u[8]; } pu;
#pragma unroll
    for (int e = 0; e < 4; ++e) { pu.u[e] = f2b(lo[e]); pu.u[4 + e] = f2b(hi[e]); }
    return pu.v;
}

// pi(r): bit permutation so swapped-QK^T D-layout == PV A-layout (no shuffles).
__device__ __forceinline__ int perm64(int r) {
    return (r & 0x23) | (((r >> 2) & 3) << 3) | (((r >> 4) & 1) << 2);
}

// async global -> LDS, 16B per lane (HW dest: wave-uniform base + lane*16)
__device__ __forceinline__ void gload16(const u16* g, u16* l) {
    __builtin_amdgcn_global_load_lds(
        (const __attribute__((address_space(1))) unsigned int*)g,
        (__attribute__((address_space(3))) unsigned int*)l,
        16, 0, 0);
}

// ---------------- K / V^T projection GEMM (W read as fp32, in-reg cvt) ----------------
__global__ __launch_bounds__(256) void gemm_kv(const float* __restrict__ x,
                                               const float* __restrict__ Wk, const float* __restrict__ Wv,
                                               const float* __restrict__ bk, const float* __restrict__ bv,
                                               u16* __restrict__ k, u16* __restrict__ vt) {
    const int tid = threadIdx.x;
    const int wid = tid >> 6, lane = tid & 63, g = lane >> 4, lq = lane & 15;
    const int m0 = blockIdx.x * 64, n0 = blockIdx.y * 64, z = blockIdx.z;
    const float* W = z ? Wv : Wk;
    const float* bias = z ? bv : bk;

    const float* arow = x + (size_t)(m0 + wid * 16 + lq) * 256;
    s16x8 af[8];
#pragma unroll
    for (int kk = 0; kk < 8; ++kk) af[kk] = pack8(arow + kk * 32 + g * 8);

    f32x4 acc[4];
#pragma unroll
    for (int nf = 0; nf < 4; ++nf) { acc[nf][0]=0.f; acc[nf][1]=0.f; acc[nf][2]=0.f; acc[nf][3]=0.f; }
#pragma unroll
    for (int kk = 0; kk < 8; ++kk) {
#pragma unroll
        for (int nf = 0; nf < 4; ++nf) {
            s16x8 b = pack8(W + (size_t)(n0 + nf * 16 + lq) * 256 + kk * 32 + g * 8);
            acc[nf] = __builtin_amdgcn_mfma_f32_16x16x32_bf16(af[kk], b, acc[nf], 0, 0, 0);
        }
    }

    __shared__ __align__(16) u16 c_lds[64 * 64];
#pragma unroll
    for (int nf = 0; nf < 4; ++nf) {
        float bb = bias[n0 + nf * 16 + lq];
#pragma unroll
        for (int j = 0; j < 4; ++j) {
            float v = acc[nf][j] + bb;
            if (!z) c_lds[(wid * 16 + (g << 2) + j) * 64 + nf * 16 + lq] = f2b(v);
            else    c_lds[(nf * 16 + lq) * 64 + wid * 16 + (g << 2) + j] = f2b(v);
        }
    }
    __syncthreads();
    if (!z) {
#pragma unroll
        for (int r = 0; r < 2; ++r) {
            int o = (r * 256 + tid) * 8, row = o >> 6, col = o & 63;
            *(s16x8*)(k + (size_t)(m0 + row) * 256 + n0 + col) = *(const s16x8*)(c_lds + row * 64 + col);
        }
    } else {
        int bidx = m0 >> 12, s0 = m0 & 4095;
#pragma unroll
        for (int r = 0; r < 2; ++r) {
            int o = (r * 256 + tid) * 8, drow = o >> 6, col = o & 63;
            *(s16x8*)(vt + (size_t)bidx * 1048576 + (size_t)(n0 + drow) * 4096 + s0 + col) =
                *(const s16x8*)(c_lds + drow * 64 + col);
        }
    }
}

// ---------------- flash attention v4 ----------------
// 8 waves (512 thr), QBLK=256, QW=32/wave, kv-split 4 (grid 64x4 = 256 blocks, 1/CU,
// 2 waves/SIMD). Q computed in-kernel from x,Wq (never materialized).
// K: [4][4096][256] bf16. VT: [4][256][4096] bf16.
// Opart: [4][16384][256] bf16 normalized partials. ml: [4][2][16384] f32.
__global__ __launch_bounds__(512) void flash4(const float* __restrict__ x, const float* __restrict__ Wq,
                                              const float* __restrict__ bq,
                                              const u16* __restrict__ K, const u16* __restrict__ VT,
                                              u16* __restrict__ Opart, float* __restrict__ ml) {
    __shared__ __align__(16) u16 smem[65536];   // 128KB
    const int tid = threadIdx.x;
    const int wid = tid >> 6, lane = tid & 63, g = lane >> 4, lqi = lane & 15;
    const int b = blockIdx.x >> 4, q0 = (blockIdx.x & 15) << 8;   // 256 q-rows / block
    const int s = blockIdx.y, kvbase = s << 10;                    // 1024 kv rows / split

    f32x4 acc[2][16];
#pragma unroll
    for (int qh = 0; qh < 2; ++qh)
#pragma unroll
        for (int nf = 0; nf < 16; ++nf) { acc[qh][nf][0]=0.f; acc[qh][nf][1]=0.f; acc[qh][nf][2]=0.f; acc[qh][nf][3]=0.f; }

    // ---- phase 1: Q projection -> q_lds (chunk-swizzled [256][256]) ----
    {
        s16x8 af[2][8];
#pragma unroll
        for (int qh = 0; qh < 2; ++qh) {
            const float* arow = x + (size_t)(b * 4096 + q0 + wid * 32 + qh * 16 + lqi) * 256;
#pragma unroll
            for (int kk = 0; kk < 8; ++kk) af[qh][kk] = pack8(arow + kk * 32 + g * 8);
        }
#pragma unroll
        for (int kk = 0; kk < 8; ++kk) {
#pragma unroll
            for (int nf = 0; nf < 16; ++nf) {
                s16x8 wb = pack8(Wq + (size_t)(nf * 16 + lqi) * 256 + kk * 32 + g * 8);
                acc[0][nf] = __builtin_amdgcn_mfma_f32_16x16x32_bf16(af[0][kk], wb, acc[0][nf], 0, 0, 0);
                acc[1][nf] = __builtin_amdgcn_mfma_f32_16x16x32_bf16(af[1][kk], wb, acc[1][nf], 0, 0, 0);
            }
        }
        const float scale = 0.0625f * 1.44269504f;   // 1/sqrt(256) * log2(e)
#pragma unroll
        for (int qh = 0; qh < 2; ++qh)
#pragma unroll
            for (int nf = 0; nf < 16; ++nf) {
                float bb = bq[nf * 16 + lqi];
#pragma unroll
                for (int j = 0; j < 4; ++j) {
                    int row = wid * 32 + qh * 16 + (g << 2) + j;
                    int col = nf * 16 + lqi;
                    int addr = row * 256 + (((col >> 3) ^ (row & 7)) << 3) + (col & 7);
                    smem[addr] = f2b((acc[qh][nf][j] + bb) * scale);
                }
            }
    }
    __syncthreads();
    s16x8 qf[2][8];
#pragma unroll
    for (int qh = 0; qh < 2; ++qh) {
        int row = wid * 32 + qh * 16 + lqi;
#pragma unroll
        for (int kk = 0; kk < 8; ++kk)
            qf[qh][kk] = *(const s16x8*)(smem + row * 256 + ((((kk << 2) | g) ^ (row & 7)) << 3));
    }
    __syncthreads();    // q_lds consumed; smem becomes K/V double-buffer

    // ---- phase 2: flash over this split's 16 KV tiles ----
#pragma unroll
    for (int qh = 0; qh < 2; ++qh)
#pragma unroll
        for (int nf = 0; nf < 16; ++nf) { acc[qh][nf][0]=0.f; acc[qh][nf][1]=0.f; acc[qh][nf][2]=0.f; acc[qh][nf][3]=0.f; }
    float mrun[2] = {-1e30f, -1e30f}, lrun[2] = {0.f, 0.f};

    const u16* kb_ = K + (size_t)b * 4096 * 256;
    const u16* vb_ = VT + (size_t)b * 256 * 4096;

    int koff[4], voff[4];
#pragma unroll
    for (int r = 0; r < 4; ++r) {
        int c = r * 512 + tid;
        int row = c >> 5, ch = c & 31;                     // K tile [64][256]
        koff[r] = perm64(row) * 256 + ((ch ^ (row & 7)) << 3);
        int vrow = c >> 3, vch = c & 7;                    // V tile [256][64]
        voff[r] = vrow * 4096 + ((vch ^ (vrow & 7)) << 3);
    }

    auto STAGE = [&](int bufsel, int t) {
        const u16* kt = kb_ + (size_t)(kvbase + (t << 6)) * 256;
        const u16* vt = vb_ + (kvbase + (t << 6));
        u16* kl = smem + bufsel * 32768;
        u16* vl = kl + 16384;
#pragma unroll
        for (int r = 0; r < 4; ++r) gload16(kt + koff[r], kl + (r * 512 + tid) * 8);
#pragma unroll
        for (int r = 0; r < 4; ++r) gload16(vt + voff[r], vl + (r * 512 + tid) * 8);
    };

    auto COMPUTE = [&](int bufsel) {
        const u16* kbuf = smem + bufsel * 32768;
        const u16* vbuf = kbuf + 16384;
        f32x4 st[2][4];
#pragma unroll
        for (int qh = 0; qh < 2; ++qh)
#pragma unroll
            for (int f = 0; f < 4; ++f) { st[qh][f][0]=0.f; st[qh][f][1]=0.f; st[qh][f][2]=0.f; st[qh][f][3]=0.f; }
        __builtin_amdgcn_s_setprio(1);
#pragma unroll
        for (int kk = 0; kk < 8; ++kk) {
#pragma unroll
            for (int f = 0; f < 4; ++f) {
                int row = f * 16 + lqi;
                s16x8 a = *(const s16x8*)(kbuf + ((row << 5) + (((kk << 2) + g) ^ (row & 7))) * 8);
                st[0][f] = __builtin_amdgcn_mfma_f32_16x16x32_bf16(a, qf[0][kk], st[0][f], 0, 0, 0);
                st[1][f] = __builtin_amdgcn_mfma_f32_16x16x32_bf16(a, qf[1][kk], st[1][f], 0, 0, 0);
            }
        }
        __builtin_amdgcn_s_setprio(0);
        // online softmax (base-2), defer-max rescale
        s16x8 pa[2][2];
#pragma unroll
        for (int qh = 0; qh < 2; ++qh) {
            float rm = -1e30f;
#pragma unroll
            for (int f = 0; f < 4; ++f)
                rm = fmaxf(rm, fmaxf(fmaxf(st[qh][f][0], st[qh][f][1]), fmaxf(st[qh][f][2], st[qh][f][3])));
            rm = fmaxf(rm, __shfl_xor(rm, 16));
            rm = fmaxf(rm, __shfl_xor(rm, 32));
            if (!__all(rm - mrun[qh] <= 8.f)) {
                float mnew = fmaxf(mrun[qh], rm);
                float alpha = exp2f(mrun[qh] - mnew);
#pragma unroll
                for (int j = 0; j < 4; ++j) {
                    float a4 = __shfl(alpha, (g << 2) + j);
#pragma unroll
                    for (int nf = 0; nf < 16; ++nf) acc[qh][nf][j] *= a4;
                }
                mrun[qh] = mnew;
                lrun[qh] *= alpha;
            }
            float ps = 0.f;
#pragma unroll
            for (int f = 0; f < 4; ++f)
#pragma unroll
                for (int j = 0; j < 4; ++j) { float e = exp2f(st[qh][f][j] - mrun[qh]); st[qh][f][j] = e; ps += e; }
            ps += __shfl_xor(ps, 16);
            ps += __shfl_xor(ps, 32);
            lrun[qh] += ps;
#pragma unroll
            for (int kk2 = 0; kk2 < 2; ++kk2) {
                union { s16x8 v; u16 u[8]; } pu;
#pragma unroll
                for (int j2 = 0; j2 < 4; ++j2) { pu.u[j2] = f2b(st[qh][2*kk2][j2]); pu.u[4+j2] = f2b(st[qh][2*kk2+1][j2]); }
                pa[qh][kk2] = pu.v;
            }
        }
        __builtin_amdgcn_s_setprio(1);
#pragma unroll
        for (int kk2 = 0; kk2 < 2; ++kk2) {
#pragma unroll
            for (int nf = 0; nf < 16; ++nf) {
                int row = (nf << 4) + lqi;
                s16x8 bv = *(const s16x8*)(vbuf + ((row << 3) + (((kk2 << 2) + g) ^ (row & 7))) * 8);
                acc[0][nf] = __builtin_amdgcn_mfma_f32_16x16x32_bf16(pa[0][kk2], bv, acc[0][nf], 0, 0, 0);
                acc[1][nf] = __builtin_amdgcn_mfma_f32_16x16x32_bf16(pa[1][kk2], bv, acc[1][nf], 0, 0, 0);
            }
        }
        __builtin_amdgcn_s_setprio(0);
    };

    STAGE(0, 0);
    for (int t2 = 0; t2 < 16; t2 += 2) {
        __syncthreads();
        STAGE(1, t2 + 1);
        COMPUTE(0);
        __syncthreads();
        if (t2 + 2 < 16) STAGE(0, t2 + 2);
        COMPUTE(1);
    }

    // epilogue
    __syncthreads();
    float linv[2][4];
#pragma unroll
    for (int qh = 0; qh < 2; ++qh)
#pragma unroll
        for (int j = 0; j < 4; ++j) linv[qh][j] = 1.0f / __shfl(lrun[qh], (g << 2) + j);
    u16* o_lds = smem;   // [256][256] bf16 = 128KB
#pragma unroll
    for (int qh = 0; qh < 2; ++qh)
#pragma unroll
        for (int nf = 0; nf < 16; ++nf)
#pragma unroll
            for (int j = 0; j < 4; ++j)
                o_lds[(wid * 32 + qh * 16 + (g << 2) + j) * 256 + (nf << 4) + lqi] = f2b(acc[qh][nf][j] * linv[qh][j]);
    __syncthreads();
    u16* orow = Opart + (size_t)s * NT + (size_t)(b * 4096 + q0) * 256;
#pragma unroll
    for (int r = 0; r < 16; ++r) {
        int o = (r * 512 + tid) * 8, row = o >> 8, col = o & 255;
        *(s16x8*)(orow + (size_t)row * 256 + col) = *(const s16x8*)(o_lds + row * 256 + col);
    }
    if (lane < 16) {
#pragma unroll
        for (int qh = 0; qh < 2; ++qh) {
            int grow = b * 4096 + q0 + wid * 32 + qh * 16 + lqi;
            ml[s * 32768 + grow]         = mrun[qh];
            ml[s * 32768 + 16384 + grow] = lrun[qh];
        }
    }
}

// ---------------- fused: recombine 4 kv-split partials + LN1(x + attn) -> h bf16 ----------------
__global__ __launch_bounds__(256) void recomb_ln1(const u16* __restrict__ Opart, const float* __restrict__ ml,
                                                  const float* __restrict__ x, const float* __restrict__ gam,
                                                  const float* __restrict__ bet, u16* __restrict__ h) {
    const int row = blockIdx.x * 4 + (threadIdx.x >> 6);
    const int lane = threadIdx.x & 63;
    float m[4], l[4];
#pragma unroll
    for (int s = 0; s < 4; ++s) { m[s] = ml[s * 32768 + row]; l[s] = ml[s * 32768 + 16384 + row]; }
    float mm = fmaxf(fmaxf(m[0], m[1]), fmaxf(m[2], m[3]));
    float a[4], tot = 0.f;
#pragma unroll
    for (int s = 0; s < 4; ++s) { a[s] = l[s] * exp2f(m[s] - mm); tot += a[s]; }
    float rs = 1.0f / tot;
    float r[4] = {0.f, 0.f, 0.f, 0.f};
#pragma unroll
    for (int s = 0; s < 4; ++s) {
        float w = a[s] * rs;
        u16x4 v = *(const u16x4*)(Opart + (size_t)s * NT + (size_t)row * 256 + lane * 4);
#pragma unroll
        for (int i = 0; i < 4; ++i) r[i] += w * b2f(v[i]);
    }
    f32x4 xv = *(const f32x4*)(x + (size_t)row * 256 + lane * 4);
    float sv[4];
#pragma unroll
    for (int i = 0; i < 4; ++i) sv[i] = xv[i] + r[i];
    float sum = sv[0] + sv[1] + sv[2] + sv[3];
    float sq = sv[0]*sv[0] + sv[1]*sv[1] + sv[2]*sv[2] + sv[3]*sv[3];
#pragma unroll
    for (int d = 1; d < 64; d <<= 1) { sum += __shfl_xor(sum, d); sq += __shfl_xor(sq, d); }
    float mean = sum * (1.f / 256.f);
    float var = sq * (1.f / 256.f) - mean * mean;
    float rstd = rsqrtf(var + 1e-5f);
    f32x4 gv = *(const f32x4*)(gam + lane * 4);
    f32x4 bv = *(const f32x4*)(bet + lane * 4);
    u16x4 y;
#pragma unroll
    for (int i = 0; i < 4; ++i) y[i] = f2b((sv[i] - mean) * rstd * gv[i] + bv[i]);
    *(u16x4*)(h + (size_t)row * 256 + lane * 4) = y;
}

// ---------------- linear GEMM: A bf16, W fp32 (in-reg cvt), K=256 ----------------
template<int RELU>
__global__ __launch_bounds__(256) void gemm_lin(const u16* __restrict__ A, const float* __restrict__ W,
                                                const float* __restrict__ bias, u16* __restrict__ Cd) {
    const int tid = threadIdx.x;
    const int wid = tid >> 6, lane = tid & 63, g = lane >> 4, lq = lane & 15;
    const int m0 = blockIdx.x * 64, n0 = blockIdx.y * 64;

    const u16* arow = A + (size_t)(m0 + wid * 16 + lq) * 256;
    f32x4 acc[4];
#pragma unroll
    for (int nf = 0; nf < 4; ++nf) { acc[nf][0]=0.f; acc[nf][1]=0.f; acc[nf][2]=0.f; acc[nf][3]=0.f; }
#pragma unroll
    for (int kk = 0; kk < 8; ++kk) {
        s16x8 a = *(const s16x8*)(arow + kk * 32 + g * 8);
#pragma unroll
        for (int nf = 0; nf < 4; ++nf) {
            s16x8 b = pack8(W + (size_t)(n0 + nf * 16 + lq) * 256 + kk * 32 + g * 8);
            acc[nf] = __builtin_amdgcn_mfma_f32_16x16x32_bf16(a, b, acc[nf], 0, 0, 0);
        }
    }
    __shared__ __align__(16) u16 c_lds[64 * 64];
#pragma unroll
    for (int nf = 0; nf < 4; ++nf) {
        float bb = bias[n0 + nf * 16 + lq];
#pragma unroll
        for (int j = 0; j < 4; ++j) {
            float v = acc[nf][j] + bb;
            if (RELU) v = fmaxf(v, 0.f);
            c_lds[(wid * 16 + (g << 2) + j) * 64 + nf * 16 + lq] = f2b(v);
        }
    }
    __syncthreads();
#pragma unroll
    for (int r = 0; r < 2; ++r) {
        int o = (r * 256 + tid) * 8, row = o >> 6, col = o & 63;
        *(s16x8*)(Cd + (size_t)(m0 + row) * 256 + n0 + col) = *(const s16x8*)(c_lds + row * 64 + col);
    }
}

// ---------------- LayerNorm(x + add) -> fp32 out ----------------
__global__ __launch_bounds__(256) void ln2_k(const float* __restrict__ x, const u16* __restrict__ add,
                                             const float* __restrict__ gam, const float* __restrict__ bet,
                                             float* __restrict__ outf) {
    const int row = blockIdx.x * 4 + (threadIdx.x >> 6);
    const int lane = threadIdx.x & 63;
    f32x4 xv = *(const f32x4*)(x + (size_t)row * 256 + lane * 4);
    u16x4 av = *(const u16x4*)(add + (size_t)row * 256 + lane * 4);
    float sv[4];
#pragma unroll
    for (int i = 0; i < 4; ++i) sv[i] = xv[i] + b2f(av[i]);
    float sum = sv[0] + sv[1] + sv[2] + sv[3];
    float sq = sv[0]*sv[0] + sv[1]*sv[1] + sv[2]*sv[2] + sv[3]*sv[3];
#pragma unroll
    for (int d = 1; d < 64; d <<= 1) { sum += __shfl_xor(sum, d); sq += __shfl_xor(sq, d); }
    float mean = sum * (1.f / 256.f);
    float var = sq * (1.f / 256.f) - mean * mean;
    float rstd = rsqrtf(var + 1e-5f);
    f32x4 gv = *(const f32x4*)(gam + lane * 4);
    f32x4 bv = *(const f32x4*)(bet + lane * 4);
    f32x4 y;
#pragma unroll
    for (int i = 0; i < 4; ++i) y[i] = (sv[i] - mean) * rstd * gv[i] + bv[i];
    *(f32x4*)(outf + (size_t)row * 256 + lane * 4) = y;
}

extern "C" void kernel_launch(void* const* d_in, const int* in_sizes, int n_in,
                              void* d_out, int out_size, void* d_ws, size_t ws_size,
                              hipStream_t stream) {
    const float* x   = (const float*)d_in[0];
    const float* Wq  = (const float*)d_in[1];
    const float* bq  = (const float*)d_in[2];
    const float* Wk  = (const float*)d_in[3];
    const float* bk  = (const float*)d_in[4];
    const float* Wv  = (const float*)d_in[5];
    const float* bv  = (const float*)d_in[6];
    const float* Wl  = (const float*)d_in[7];
    const float* bl  = (const float*)d_in[8];
    const float* g1  = (const float*)d_in[9];
    const float* be1 = (const float*)d_in[10];
    const float* g2  = (const float*)d_in[11];
    const float* be2 = (const float*)d_in[12];
    float* out = (float*)d_out;

    // ws (u16 units): kb [NT] k -> h ; vtb [NT] vT -> h1 ; op [4NT] partials -> h2 ;
    // ml [4][2][16384] f32. Total 50.9 MB.
    u16* kb   = (u16*)d_ws;
    u16* vtb  = kb + NT;
    u16* op   = vtb + NT;
    float* ml = (float*)(op + (size_t)4 * NT);

    gemm_kv<<<dim3(256, 4, 2), 256, 0, stream>>>(x, Wk, Wv, bk, bv, kb, vtb);

    flash4<<<dim3(64, 4), 512, 0, stream>>>(x, Wq, bq, kb, vtb, op, ml);

    recomb_ln1<<<4096, 256, 0, stream>>>(op, ml, x, g1, be1, kb /* h */);

    dim3 ggrid(256, 4);
    gemm_lin<1><<<ggrid, 256, 0, stream>>>(kb, Wl, bl, vtb /* h1 */);
    gemm_lin<0><<<ggrid, 256, 0, stream>>>(vtb, Wl, bl, op /* h2 */);

    ln2_k<<<4096, 256, 0, stream>>>(x, op, g2, be2, out);
}

// Round 6
// 443.699 us; speedup vs baseline: 1.4022x; 1.4022x over previous
//
#include <hip/hip_runtime.h>

typedef unsigned short u16;
typedef float  f32x4 __attribute__((ext_vector_type(4)));
typedef short  s16x8 __attribute__((ext_vector_type(8)));
typedef unsigned short u16x4 __attribute__((ext_vector_type(4)));

#define NT 4194304   // 16384*256 token-matrix elements

__device__ __forceinline__ u16 f2b(float f) {
    unsigned b = __float_as_uint(f);
    return (u16)((b + 0x7FFFu + ((b >> 16) & 1u)) >> 16);   // RNE
}
__device__ __forceinline__ float b2f(u16 u) { return __uint_as_float(((unsigned)u) << 16); }

// pack 8 consecutive fp32 -> bf16x8 fragment
__device__ __forceinline__ s16x8 pack8(const float* p) {
    f32x4 lo = *(const f32x4*)p, hi = *(const f32x4*)(p + 4);
    union { s16x8 v; u16 u[8]; } pu;
#pragma unroll
    for (int e = 0; e < 4; ++e) { pu.u[e] = f2b(lo[e]); pu.u[4 + e] = f2b(hi[e]); }
    return pu.v;
}

// pi(r): bit permutation so swapped-QK^T D-layout == PV A-layout (no shuffles).
// r<32: f<<4|g<<2|j -> g<<3|f<<2|j  (same swap as the 64-row variant, bit5 untouched)
__device__ __forceinline__ int perm64(int r) {
    return (r & 0x23) | (((r >> 2) & 3) << 3) | (((r >> 4) & 1) << 2);
}

// async global -> LDS, 16B per lane (HW dest: wave-uniform base + lane*16)
__device__ __forceinline__ void gload16(const u16* g, u16* l) {
    __builtin_amdgcn_global_load_lds(
        (const __attribute__((address_space(1))) unsigned int*)g,
        (__attribute__((address_space(3))) unsigned int*)l,
        16, 0, 0);
}

// ---------------- K / V^T projection GEMM (W read as fp32, in-reg cvt) ----------------
__global__ __launch_bounds__(256) void gemm_kv(const float* __restrict__ x,
                                               const float* __restrict__ Wk, const float* __restrict__ Wv,
                                               const float* __restrict__ bk, const float* __restrict__ bv,
                                               u16* __restrict__ k, u16* __restrict__ vt) {
    const int tid = threadIdx.x;
    const int wid = tid >> 6, lane = tid & 63, g = lane >> 4, lq = lane & 15;
    const int m0 = blockIdx.x * 64, n0 = blockIdx.y * 64, z = blockIdx.z;
    const float* W = z ? Wv : Wk;
    const float* bias = z ? bv : bk;

    const float* arow = x + (size_t)(m0 + wid * 16 + lq) * 256;
    s16x8 af[8];
#pragma unroll
    for (int kk = 0; kk < 8; ++kk) af[kk] = pack8(arow + kk * 32 + g * 8);

    f32x4 acc[4];
#pragma unroll
    for (int nf = 0; nf < 4; ++nf) { acc[nf][0]=0.f; acc[nf][1]=0.f; acc[nf][2]=0.f; acc[nf][3]=0.f; }
#pragma unroll
    for (int kk = 0; kk < 8; ++kk) {
#pragma unroll
        for (int nf = 0; nf < 4; ++nf) {
            s16x8 b = pack8(W + (size_t)(n0 + nf * 16 + lq) * 256 + kk * 32 + g * 8);
            acc[nf] = __builtin_amdgcn_mfma_f32_16x16x32_bf16(af[kk], b, acc[nf], 0, 0, 0);
        }
    }

    __shared__ __align__(16) u16 c_lds[64 * 64];
#pragma unroll
    for (int nf = 0; nf < 4; ++nf) {
        float bb = bias[n0 + nf * 16 + lq];
#pragma unroll
        for (int j = 0; j < 4; ++j) {
            float v = acc[nf][j] + bb;
            if (!z) c_lds[(wid * 16 + (g << 2) + j) * 64 + nf * 16 + lq] = f2b(v);
            else    c_lds[(nf * 16 + lq) * 64 + wid * 16 + (g << 2) + j] = f2b(v);
        }
    }
    __syncthreads();
    if (!z) {
#pragma unroll
        for (int r = 0; r < 2; ++r) {
            int o = (r * 256 + tid) * 8, row = o >> 6, col = o & 63;
            *(s16x8*)(k + (size_t)(m0 + row) * 256 + n0 + col) = *(const s16x8*)(c_lds + row * 64 + col);
        }
    } else {
        int bidx = m0 >> 12, s0 = m0 & 4095;
#pragma unroll
        for (int r = 0; r < 2; ++r) {
            int o = (r * 256 + tid) * 8, drow = o >> 6, col = o & 63;
            *(s16x8*)(vt + (size_t)bidx * 1048576 + (size_t)(n0 + drow) * 4096 + s0 + col) =
                *(const s16x8*)(c_lds + drow * 64 + col);
        }
    }
}

// ---------------- flash attention v5 ----------------
// 256 thr (4 waves), QBLK=128, QW=32/wave, KVBLK=32, dbuf 64KB LDS -> 2 blocks/CU
// (2 waves/SIMD), kv-split 4 (grid 128x4 = 512 blocks). Q computed in-kernel.
// K: [4][4096][256] bf16. VT: [4][256][4096] bf16.
// Opart: [4][16384][256] bf16 normalized partials. ml: [4][2][16384] f32.
__global__ __launch_bounds__(256) void flash5(const float* __restrict__ x, const float* __restrict__ Wq,
                                              const float* __restrict__ bq,
                                              const u16* __restrict__ K, const u16* __restrict__ VT,
                                              u16* __restrict__ Opart, float* __restrict__ ml) {
    __shared__ __align__(16) u16 smem[32768];   // 64KB
    const int tid = threadIdx.x;
    const int wid = tid >> 6, lane = tid & 63, g = lane >> 4, lqi = lane & 15;
    const int b = blockIdx.x >> 5, q0 = (blockIdx.x & 31) << 7;   // 128 q-rows / block
    const int s = blockIdx.y, kvbase = s << 10;                    // 1024 kv rows / split

    f32x4 acc[2][16];
#pragma unroll
    for (int qh = 0; qh < 2; ++qh)
#pragma unroll
        for (int nf = 0; nf < 16; ++nf) { acc[qh][nf][0]=0.f; acc[qh][nf][1]=0.f; acc[qh][nf][2]=0.f; acc[qh][nf][3]=0.f; }

    // ---- phase 1: Q projection -> q_lds [128][256] (chunk-swizzled), then to regs ----
    {
        s16x8 af[2][8];
#pragma unroll
        for (int qh = 0; qh < 2; ++qh) {
            const float* arow = x + (size_t)(b * 4096 + q0 + wid * 32 + qh * 16 + lqi) * 256;
#pragma unroll
            for (int kk = 0; kk < 8; ++kk) af[qh][kk] = pack8(arow + kk * 32 + g * 8);
        }
#pragma unroll
        for (int kk = 0; kk < 8; ++kk) {
#pragma unroll
            for (int nf = 0; nf < 16; ++nf) {
                s16x8 wb = pack8(Wq + (size_t)(nf * 16 + lqi) * 256 + kk * 32 + g * 8);
                acc[0][nf] = __builtin_amdgcn_mfma_f32_16x16x32_bf16(af[0][kk], wb, acc[0][nf], 0, 0, 0);
                acc[1][nf] = __builtin_amdgcn_mfma_f32_16x16x32_bf16(af[1][kk], wb, acc[1][nf], 0, 0, 0);
            }
        }
        const float scale = 0.0625f * 1.44269504f;   // 1/sqrt(256) * log2(e)
#pragma unroll
        for (int qh = 0; qh < 2; ++qh)
#pragma unroll
            for (int nf = 0; nf < 16; ++nf) {
                float bb = bq[nf * 16 + lqi];
#pragma unroll
                for (int j = 0; j < 4; ++j) {
                    int row = wid * 32 + qh * 16 + (g << 2) + j;
                    int col = nf * 16 + lqi;
                    int addr = row * 256 + (((col >> 3) ^ (row & 7)) << 3) + (col & 7);
                    smem[addr] = f2b((acc[qh][nf][j] + bb) * scale);
                }
            }
    }
    __syncthreads();
    s16x8 qf[2][8];
#pragma unroll
    for (int qh = 0; qh < 2; ++qh) {
        int row = wid * 32 + qh * 16 + lqi;
#pragma unroll
        for (int kk = 0; kk < 8; ++kk)
            qf[qh][kk] = *(const s16x8*)(smem + row * 256 + ((((kk << 2) | g) ^ (row & 7)) << 3));
    }
    __syncthreads();    // q_lds consumed; smem becomes K/V double-buffer

    // ---- phase 2: flash over this split's 32 KV tiles (KVBLK=32) ----
#pragma unroll
    for (int qh = 0; qh < 2; ++qh)
#pragma unroll
        for (int nf = 0; nf < 16; ++nf) { acc[qh][nf][0]=0.f; acc[qh][nf][1]=0.f; acc[qh][nf][2]=0.f; acc[qh][nf][3]=0.f; }
    float mrun[2] = {-1e30f, -1e30f}, lrun[2] = {0.f, 0.f};

    const u16* kb_ = K + (size_t)b * 4096 * 256;
    const u16* vb_ = VT + (size_t)b * 256 * 4096;

    // staging source offsets (u16 units). K tile [32][256]: 1024 16B-chunks; V tile [256][32]: 1024.
    int koff[4], voff[4];
#pragma unroll
    for (int r = 0; r < 4; ++r) {
        int c = r * 256 + tid;
        int row = c >> 5, ch = c & 31;                     // K: 32 chunks/row
        koff[r] = perm64(row) * 256 + ((ch ^ (row & 7)) << 3);
        int vrow = c >> 2, vch = c & 3;                    // V: 4 chunks/row
        voff[r] = vrow * 4096 + ((vch ^ ((vrow >> 1) & 3)) << 3);
    }

    auto STAGE = [&](int bufsel, int t) {
        const u16* kt = kb_ + (size_t)(kvbase + (t << 5)) * 256;
        const u16* vt = vb_ + (kvbase + (t << 5));
        u16* kl = smem + bufsel * 16384;
        u16* vl = kl + 8192;
#pragma unroll
        for (int r = 0; r < 4; ++r) gload16(kt + koff[r], kl + (r * 256 + tid) * 8);
#pragma unroll
        for (int r = 0; r < 4; ++r) gload16(vt + voff[r], vl + (r * 256 + tid) * 8);
    };

    auto COMPUTE = [&](int bufsel) {
        const u16* kbuf = smem + bufsel * 16384;
        const u16* vbuf = kbuf + 8192;
        // ST = K . Q^T   (st[qh][f]: lane holds S[kv-slot f*16+g*4+j][q=lqi])
        f32x4 st[2][2];
#pragma unroll
        for (int qh = 0; qh < 2; ++qh)
#pragma unroll
            for (int f = 0; f < 2; ++f) { st[qh][f][0]=0.f; st[qh][f][1]=0.f; st[qh][f][2]=0.f; st[qh][f][3]=0.f; }
        __builtin_amdgcn_s_setprio(1);
#pragma unroll
        for (int kk = 0; kk < 8; ++kk) {
#pragma unroll
            for (int f = 0; f < 2; ++f) {
                int row = f * 16 + lqi;
                s16x8 a = *(const s16x8*)(kbuf + ((row << 5) + (((kk << 2) + g) ^ (row & 7))) * 8);
                st[0][f] = __builtin_amdgcn_mfma_f32_16x16x32_bf16(a, qf[0][kk], st[0][f], 0, 0, 0);
                st[1][f] = __builtin_amdgcn_mfma_f32_16x16x32_bf16(a, qf[1][kk], st[1][f], 0, 0, 0);
            }
        }
        __builtin_amdgcn_s_setprio(0);
        // online softmax (base-2), defer-max rescale
        s16x8 pa[2];
#pragma unroll
        for (int qh = 0; qh < 2; ++qh) {
            float rm = fmaxf(fmaxf(st[qh][0][0], st[qh][0][1]), fmaxf(st[qh][0][2], st[qh][0][3]));
            rm = fmaxf(rm, fmaxf(fmaxf(st[qh][1][0], st[qh][1][1]), fmaxf(st[qh][1][2], st[qh][1][3])));
            rm = fmaxf(rm, __shfl_xor(rm, 16));
            rm = fmaxf(rm, __shfl_xor(rm, 32));
            if (!__all(rm - mrun[qh] <= 8.f)) {
                float mnew = fmaxf(mrun[qh], rm);
                float alpha = exp2f(mrun[qh] - mnew);
#pragma unroll
                for (int j = 0; j < 4; ++j) {
                    float a4 = __shfl(alpha, (g << 2) + j);
#pragma unroll
                    for (int nf = 0; nf < 16; ++nf) acc[qh][nf][j] *= a4;
                }
                mrun[qh] = mnew;
                lrun[qh] *= alpha;
            }
            float ps = 0.f;
#pragma unroll
            for (int f = 0; f < 2; ++f)
#pragma unroll
                for (int j = 0; j < 4; ++j) { float e = exp2f(st[qh][f][j] - mrun[qh]); st[qh][f][j] = e; ps += e; }
            ps += __shfl_xor(ps, 16);
            ps += __shfl_xor(ps, 32);
            lrun[qh] += ps;
            // P pack: lane holds P[q=lqi][kv = g*8 + e]; e=f*4+j (perm32-staged K makes this local)
            union { s16x8 v; u16 u[8]; } pu;
#pragma unroll
            for (int j2 = 0; j2 < 4; ++j2) { pu.u[j2] = f2b(st[qh][0][j2]); pu.u[4+j2] = f2b(st[qh][1][j2]); }
            pa[qh] = pu.v;
        }
        // PV: single k-step (KVBLK=32)
        __builtin_amdgcn_s_setprio(1);
#pragma unroll
        for (int nf = 0; nf < 16; ++nf) {
            int row = (nf << 4) + lqi;
            s16x8 bv = *(const s16x8*)(vbuf + ((row << 2) + (g ^ ((row >> 1) & 3))) * 8);
            acc[0][nf] = __builtin_amdgcn_mfma_f32_16x16x32_bf16(pa[0], bv, acc[0][nf], 0, 0, 0);
            acc[1][nf] = __builtin_amdgcn_mfma_f32_16x16x32_bf16(pa[1], bv, acc[1][nf], 0, 0, 0);
        }
        __builtin_amdgcn_s_setprio(0);
    };

    STAGE(0, 0);
    for (int t2 = 0; t2 < 32; t2 += 2) {
        __syncthreads();
        STAGE(1, t2 + 1);
        COMPUTE(0);
        __syncthreads();
        if (t2 + 2 < 32) STAGE(0, t2 + 2);
        COMPUTE(1);
    }

    // epilogue
    __syncthreads();
    float linv[2][4];
#pragma unroll
    for (int qh = 0; qh < 2; ++qh)
#pragma unroll
        for (int j = 0; j < 4; ++j) linv[qh][j] = 1.0f / __shfl(lrun[qh], (g << 2) + j);
    u16* o_lds = smem;   // [128][256] bf16 = 64KB
#pragma unroll
    for (int qh = 0; qh < 2; ++qh)
#pragma unroll
        for (int nf = 0; nf < 16; ++nf)
#pragma unroll
            for (int j = 0; j < 4; ++j)
                o_lds[(wid * 32 + qh * 16 + (g << 2) + j) * 256 + (nf << 4) + lqi] = f2b(acc[qh][nf][j] * linv[qh][j]);
    __syncthreads();
    u16* orow = Opart + (size_t)s * NT + (size_t)(b * 4096 + q0) * 256;
#pragma unroll
    for (int r = 0; r < 16; ++r) {
        int o = (r * 256 + tid) * 8, row = o >> 8, col = o & 255;
        *(s16x8*)(orow + (size_t)row * 256 + col) = *(const s16x8*)(o_lds + row * 256 + col);
    }
    if (lane < 16) {
#pragma unroll
        for (int qh = 0; qh < 2; ++qh) {
            int grow = b * 4096 + q0 + wid * 32 + qh * 16 + lqi;
            ml[s * 32768 + grow]         = mrun[qh];
            ml[s * 32768 + 16384 + grow] = lrun[qh];
        }
    }
}

// ---------------- fused: recombine 4 kv-split partials + LN1(x + attn) -> h bf16 ----------------
__global__ __launch_bounds__(256) void recomb_ln1(const u16* __restrict__ Opart, const float* __restrict__ ml,
                                                  const float* __restrict__ x, const float* __restrict__ gam,
                                                  const float* __restrict__ bet, u16* __restrict__ h) {
    const int row = blockIdx.x * 4 + (threadIdx.x >> 6);
    const int lane = threadIdx.x & 63;
    float m[4], l[4];
#pragma unroll
    for (int s = 0; s < 4; ++s) { m[s] = ml[s * 32768 + row]; l[s] = ml[s * 32768 + 16384 + row]; }
    float mm = fmaxf(fmaxf(m[0], m[1]), fmaxf(m[2], m[3]));
    float a[4], tot = 0.f;
#pragma unroll
    for (int s = 0; s < 4; ++s) { a[s] = l[s] * exp2f(m[s] - mm); tot += a[s]; }
    float rs = 1.0f / tot;
    float r[4] = {0.f, 0.f, 0.f, 0.f};
#pragma unroll
    for (int s = 0; s < 4; ++s) {
        float w = a[s] * rs;
        u16x4 v = *(const u16x4*)(Opart + (size_t)s * NT + (size_t)row * 256 + lane * 4);
#pragma unroll
        for (int i = 0; i < 4; ++i) r[i] += w * b2f(v[i]);
    }
    f32x4 xv = *(const f32x4*)(x + (size_t)row * 256 + lane * 4);
    float sv[4];
#pragma unroll
    for (int i = 0; i < 4; ++i) sv[i] = xv[i] + r[i];
    float sum = sv[0] + sv[1] + sv[2] + sv[3];
    float sq = sv[0]*sv[0] + sv[1]*sv[1] + sv[2]*sv[2] + sv[3]*sv[3];
#pragma unroll
    for (int d = 1; d < 64; d <<= 1) { sum += __shfl_xor(sum, d); sq += __shfl_xor(sq, d); }
    float mean = sum * (1.f / 256.f);
    float var = sq * (1.f / 256.f) - mean * mean;
    float rstd = rsqrtf(var + 1e-5f);
    f32x4 gv = *(const f32x4*)(gam + lane * 4);
    f32x4 bv = *(const f32x4*)(bet + lane * 4);
    u16x4 y;
#pragma unroll
    for (int i = 0; i < 4; ++i) y[i] = f2b((sv[i] - mean) * rstd * gv[i] + bv[i]);
    *(u16x4*)(h + (size_t)row * 256 + lane * 4) = y;
}

// ---------------- linear GEMM: A bf16, W fp32 (in-reg cvt), K=256 ----------------
template<int RELU>
__global__ __launch_bounds__(256) void gemm_lin(const u16* __restrict__ A, const float* __restrict__ W,
                                                const float* __restrict__ bias, u16* __restrict__ Cd) {
    const int tid = threadIdx.x;
    const int wid = tid >> 6, lane = tid & 63, g = lane >> 4, lq = lane & 15;
    const int m0 = blockIdx.x * 64, n0 = blockIdx.y * 64;

    const u16* arow = A + (size_t)(m0 + wid * 16 + lq) * 256;
    f32x4 acc[4];
#pragma unroll
    for (int nf = 0; nf < 4; ++nf) { acc[nf][0]=0.f; acc[nf][1]=0.f; acc[nf][2]=0.f; acc[nf][3]=0.f; }
#pragma unroll
    for (int kk = 0; kk < 8; ++kk) {
        s16x8 a = *(const s16x8*)(arow + kk * 32 + g * 8);
#pragma unroll
        for (int nf = 0; nf < 4; ++nf) {
            s16x8 b = pack8(W + (size_t)(n0 + nf * 16 + lq) * 256 + kk * 32 + g * 8);
            acc[nf] = __builtin_amdgcn_mfma_f32_16x16x32_bf16(a, b, acc[nf], 0, 0, 0);
        }
    }
    __shared__ __align__(16) u16 c_lds[64 * 64];
#pragma unroll
    for (int nf = 0; nf < 4; ++nf) {
        float bb = bias[n0 + nf * 16 + lq];
#pragma unroll
        for (int j = 0; j < 4; ++j) {
            float v = acc[nf][j] + bb;
            if (RELU) v = fmaxf(v, 0.f);
            c_lds[(wid * 16 + (g << 2) + j) * 64 + nf * 16 + lq] = f2b(v);
        }
    }
    __syncthreads();
#pragma unroll
    for (int r = 0; r < 2; ++r) {
        int o = (r * 256 + tid) * 8, row = o >> 6, col = o & 63;
        *(s16x8*)(Cd + (size_t)(m0 + row) * 256 + n0 + col) = *(const s16x8*)(c_lds + row * 64 + col);
    }
}

// ---------------- LayerNorm(x + add) -> fp32 out ----------------
__global__ __launch_bounds__(256) void ln2_k(const float* __restrict__ x, const u16* __restrict__ add,
                                             const float* __restrict__ gam, const float* __restrict__ bet,
                                             float* __restrict__ outf) {
    const int row = blockIdx.x * 4 + (threadIdx.x >> 6);
    const int lane = threadIdx.x & 63;
    f32x4 xv = *(const f32x4*)(x + (size_t)row * 256 + lane * 4);
    u16x4 av = *(const u16x4*)(add + (size_t)row * 256 + lane * 4);
    float sv[4];
#pragma unroll
    for (int i = 0; i < 4; ++i) sv[i] = xv[i] + b2f(av[i]);
    float sum = sv[0] + sv[1] + sv[2] + sv[3];
    float sq = sv[0]*sv[0] + sv[1]*sv[1] + sv[2]*sv[2] + sv[3]*sv[3];
#pragma unroll
    for (int d = 1; d < 64; d <<= 1) { sum += __shfl_xor(sum, d); sq += __shfl_xor(sq, d); }
    float mean = sum * (1.f / 256.f);
    float var = sq * (1.f / 256.f) - mean * mean;
    float rstd = rsqrtf(var + 1e-5f);
    f32x4 gv = *(const f32x4*)(gam + lane * 4);
    f32x4 bv = *(const f32x4*)(bet + lane * 4);
    f32x4 y;
#pragma unroll
    for (int i = 0; i < 4; ++i) y[i] = (sv[i] - mean) * rstd * gv[i] + bv[i];
    *(f32x4*)(outf + (size_t)row * 256 + lane * 4) = y;
}

extern "C" void kernel_launch(void* const* d_in, const int* in_sizes, int n_in,
                              void* d_out, int out_size, void* d_ws, size_t ws_size,
                              hipStream_t stream) {
    const float* x   = (const float*)d_in[0];
    const float* Wq  = (const float*)d_in[1];
    const float* bq  = (const float*)d_in[2];
    const float* Wk  = (const float*)d_in[3];
    const float* bk  = (const float*)d_in[4];
    const float* Wv  = (const float*)d_in[5];
    const float* bv  = (const float*)d_in[6];
    const float* Wl  = (const float*)d_in[7];
    const float* bl  = (const float*)d_in[8];
    const float* g1  = (const float*)d_in[9];
    const float* be1 = (const float*)d_in[10];
    const float* g2  = (const float*)d_in[11];
    const float* be2 = (const float*)d_in[12];
    float* out = (float*)d_out;

    // ws (u16 units): kb [NT] k -> h ; vtb [NT] vT -> h1 ; op [4NT] partials -> h2 ;
    // ml [4][2][16384] f32. Total 50.9 MB (proven footprint).
    u16* kb   = (u16*)d_ws;
    u16* vtb  = kb + NT;
    u16* op   = vtb + NT;
    float* ml = (float*)(op + (size_t)4 * NT);

    gemm_kv<<<dim3(256, 4, 2), 256, 0, stream>>>(x, Wk, Wv, bk, bv, kb, vtb);

    flash5<<<dim3(128, 4), 256, 0, stream>>>(x, Wq, bq, kb, vtb, op, ml);

    recomb_ln1<<<4096, 256, 0, stream>>>(op, ml, x, g1, be1, kb /* h */);

    dim3 ggrid(256, 4);
    gemm_lin<1><<<ggrid, 256, 0, stream>>>(kb, Wl, bl, vtb /* h1 */);
    gemm_lin<0><<<ggrid, 256, 0, stream>>>(vtb, Wl, bl, op /* h2 */);

    ln2_k<<<4096, 256, 0, stream>>>(x, op, g2, be2, out);
}

// Round 7
// 390.010 us; speedup vs baseline: 1.5952x; 1.1377x over previous
//
#include <hip/hip_runtime.h>

typedef unsigned short u16;
typedef float  f32x4 __attribute__((ext_vector_type(4)));
typedef short  s16x8 __attribute__((ext_vector_type(8)));
typedef unsigned short u16x4 __attribute__((ext_vector_type(4)));

#define NT 4194304   // 16384*256 token-matrix elements

__device__ __forceinline__ u16 f2b(float f) {
    unsigned b = __float_as_uint(f);
    return (u16)((b + 0x7FFFu + ((b >> 16) & 1u)) >> 16);   // RNE
}
__device__ __forceinline__ float b2f(u16 u) { return __uint_as_float(((unsigned)u) << 16); }

__device__ __forceinline__ s16x8 pack8(const float* p) {
    f32x4 lo = *(const f32x4*)p, hi = *(const f32x4*)(p + 4);
    union { s16x8 v; u16 u[8]; } pu;
#pragma unroll
    for (int e = 0; e < 4; ++e) { pu.u[e] = f2b(lo[e]); pu.u[4 + e] = f2b(hi[e]); }
    return pu.v;
}

// pi(r): bit permutation so swapped-QK^T D-layout == PV A-layout (rows < 32: bit5=0)
__device__ __forceinline__ int perm64(int r) {
    return (r & 0x23) | (((r >> 2) & 3) << 3) | (((r >> 4) & 1) << 2);
}

__device__ __forceinline__ void gload16(const u16* g, u16* l) {
    __builtin_amdgcn_global_load_lds(
        (const __attribute__((address_space(1))) unsigned int*)g,
        (__attribute__((address_space(3))) unsigned int*)l,
        16, 0, 0);
}

// ---------------- convert 4 weight matrices fp32 -> bf16, one launch ----------------
__global__ __launch_bounds__(256) void cvt_w4(const float* __restrict__ w0, const float* __restrict__ w1,
                                              const float* __restrict__ w2, const float* __restrict__ w3,
                                              u16* __restrict__ dst) {
    const int z = blockIdx.y;
    const float* src = z == 0 ? w0 : z == 1 ? w1 : z == 2 ? w2 : w3;
    int i = (blockIdx.x * 256 + threadIdx.x) * 4;
    f32x4 v = *(const f32x4*)(src + i);
    u16x4 o;
    o[0] = f2b(v[0]); o[1] = f2b(v[1]); o[2] = f2b(v[2]); o[3] = f2b(v[3]);
    *(u16x4*)(dst + (size_t)z * 65536 + i) = o;
}

// ---------------- K / V^T projection GEMM (bf16 W) ----------------
__global__ __launch_bounds__(256) void gemm_kv(const float* __restrict__ x, const u16* __restrict__ wk,
                                               const u16* __restrict__ wv,
                                               const float* __restrict__ bk, const float* __restrict__ bv,
                                               u16* __restrict__ k, u16* __restrict__ vt) {
    const int tid = threadIdx.x;
    const int wid = tid >> 6, lane = tid & 63, g = lane >> 4, lq = lane & 15;
    const int m0 = blockIdx.x * 64, n0 = blockIdx.y * 64, z = blockIdx.z;
    const u16* W = z ? wv : wk;
    const float* bias = z ? bv : bk;

    const float* arow = x + (size_t)(m0 + wid * 16 + lq) * 256;
    s16x8 af[8];
#pragma unroll
    for (int kk = 0; kk < 8; ++kk) af[kk] = pack8(arow + kk * 32 + g * 8);

    f32x4 acc[4];
#pragma unroll
    for (int nf = 0; nf < 4; ++nf) { acc[nf][0]=0.f; acc[nf][1]=0.f; acc[nf][2]=0.f; acc[nf][3]=0.f; }
#pragma unroll
    for (int kk = 0; kk < 8; ++kk) {
#pragma unroll
        for (int nf = 0; nf < 4; ++nf) {
            s16x8 b = *(const s16x8*)(W + (size_t)(n0 + nf * 16 + lq) * 256 + kk * 32 + g * 8);
            acc[nf] = __builtin_amdgcn_mfma_f32_16x16x32_bf16(af[kk], b, acc[nf], 0, 0, 0);
        }
    }

    __shared__ __align__(16) u16 c_lds[64 * 64];
#pragma unroll
    for (int nf = 0; nf < 4; ++nf) {
        float bb = bias[n0 + nf * 16 + lq];
#pragma unroll
        for (int j = 0; j < 4; ++j) {
            float v = acc[nf][j] + bb;
            if (!z) c_lds[(wid * 16 + (g << 2) + j) * 64 + nf * 16 + lq] = f2b(v);
            else    c_lds[(nf * 16 + lq) * 64 + wid * 16 + (g << 2) + j] = f2b(v);
        }
    }
    __syncthreads();
    if (!z) {
#pragma unroll
        for (int r = 0; r < 2; ++r) {
            int o = (r * 256 + tid) * 8, row = o >> 6, col = o & 63;
            *(s16x8*)(k + (size_t)(m0 + row) * 256 + n0 + col) = *(const s16x8*)(c_lds + row * 64 + col);
        }
    } else {
        int bidx = m0 >> 12, s0 = m0 & 4095;
#pragma unroll
        for (int r = 0; r < 2; ++r) {
            int o = (r * 256 + tid) * 8, drow = o >> 6, col = o & 63;
            *(s16x8*)(vt + (size_t)bidx * 1048576 + (size_t)(n0 + drow) * 4096 + s0 + col) =
                *(const s16x8*)(c_lds + drow * 64 + col);
        }
    }
}

// ---------------- flash attention v6: QW=16 (low-reg), 2 blocks/CU target ----------------
// 256 thr (4 waves), QBLK=64, KVBLK=32, dbuf 64KB LDS, kv-split 2 (grid 256x2 = 512).
// Q computed in-kernel from x,WqB (bf16). K: [4][4096][256]. VT: [4][256][4096].
// Opart: [2][16384][256] bf16 normalized partials. ml: [2][2][16384] f32.
__global__ __launch_bounds__(256) void flash6(const float* __restrict__ x, const u16* __restrict__ wq,
                                              const float* __restrict__ bq,
                                              const u16* __restrict__ K, const u16* __restrict__ VT,
                                              u16* __restrict__ Opart, float* __restrict__ ml) {
    __shared__ __align__(16) u16 smem[32768];   // 64KB
    const int tid = threadIdx.x;
    const int wid = tid >> 6, lane = tid & 63, g = lane >> 4, lqi = lane & 15;
    const int b = blockIdx.x >> 6, q0 = (blockIdx.x & 63) << 6;   // 64 q-rows / block
    const int s = blockIdx.y, kvbase = s << 11;                    // 2048 kv rows / split

    f32x4 acc[16];
#pragma unroll
    for (int nf = 0; nf < 16; ++nf) { acc[nf][0]=0.f; acc[nf][1]=0.f; acc[nf][2]=0.f; acc[nf][3]=0.f; }

    // ---- phase 1: Q projection (16 rows/wave) -> q_lds [64][256] swizzled ----
    {
        const float* arow = x + (size_t)(b * 4096 + q0 + wid * 16 + lqi) * 256;
        s16x8 af[8];
#pragma unroll
        for (int kk = 0; kk < 8; ++kk) af[kk] = pack8(arow + kk * 32 + g * 8);
#pragma unroll
        for (int kk = 0; kk < 8; ++kk)
#pragma unroll
            for (int nf = 0; nf < 16; ++nf) {
                s16x8 wb = *(const s16x8*)(wq + (size_t)(nf * 16 + lqi) * 256 + kk * 32 + g * 8);
                acc[nf] = __builtin_amdgcn_mfma_f32_16x16x32_bf16(af[kk], wb, acc[nf], 0, 0, 0);
            }
        const float scale = 0.0625f * 1.44269504f;   // 1/sqrt(256) * log2(e)
#pragma unroll
        for (int nf = 0; nf < 16; ++nf) {
            float bb = bq[nf * 16 + lqi];
#pragma unroll
            for (int j = 0; j < 4; ++j) {
                int row = wid * 16 + (g << 2) + j;
                int col = nf * 16 + lqi;
                int addr = row * 256 + (((col >> 3) ^ (row & 7)) << 3) + (col & 7);
                smem[addr] = f2b((acc[nf][j] + bb) * scale);
            }
        }
    }
    __syncthreads();
    s16x8 qf[8];
    {
        int row = wid * 16 + lqi;
#pragma unroll
        for (int kk = 0; kk < 8; ++kk)
            qf[kk] = *(const s16x8*)(smem + row * 256 + ((((kk << 2) | g) ^ (row & 7)) << 3));
    }
    __syncthreads();    // q_lds consumed; smem becomes K/V double-buffer

    // ---- phase 2: flash over this split's 64 KV tiles (KVBLK=32) ----
#pragma unroll
    for (int nf = 0; nf < 16; ++nf) { acc[nf][0]=0.f; acc[nf][1]=0.f; acc[nf][2]=0.f; acc[nf][3]=0.f; }
    float mrun = -1e30f, lrun = 0.f;

    const u16* kb_ = K + (size_t)b * 4096 * 256;
    const u16* vb_ = VT + (size_t)b * 256 * 4096;

    int koff[4], voff[4];
#pragma unroll
    for (int r = 0; r < 4; ++r) {
        int c = r * 256 + tid;
        int row = c >> 5, ch = c & 31;                     // K tile [32][256]
        koff[r] = perm64(row) * 256 + ((ch ^ (row & 7)) << 3);
        int vrow = c >> 2, vch = c & 3;                    // V tile [256][32]
        voff[r] = vrow * 4096 + ((vch ^ ((vrow >> 1) & 3)) << 3);
    }

    auto STAGE = [&](int bufsel, int t) {
        const u16* kt = kb_ + (size_t)(kvbase + (t << 5)) * 256;
        const u16* vt = vb_ + (kvbase + (t << 5));
        u16* kl = smem + bufsel * 16384;
        u16* vl = kl + 8192;
#pragma unroll
        for (int r = 0; r < 4; ++r) gload16(kt + koff[r], kl + (r * 256 + tid) * 8);
#pragma unroll
        for (int r = 0; r < 4; ++r) gload16(vt + voff[r], vl + (r * 256 + tid) * 8);
    };

    auto COMPUTE = [&](int bufsel) {
        const u16* kbuf = smem + bufsel * 16384;
        const u16* vbuf = kbuf + 8192;
        f32x4 st[2];
#pragma unroll
        for (int f = 0; f < 2; ++f) { st[f][0]=0.f; st[f][1]=0.f; st[f][2]=0.f; st[f][3]=0.f; }
        __builtin_amdgcn_s_setprio(1);
#pragma unroll
        for (int kk = 0; kk < 8; ++kk) {
#pragma unroll
            for (int f = 0; f < 2; ++f) {
                int row = f * 16 + lqi;
                s16x8 a = *(const s16x8*)(kbuf + ((row << 5) + (((kk << 2) + g) ^ (row & 7))) * 8);
                st[f] = __builtin_amdgcn_mfma_f32_16x16x32_bf16(a, qf[kk], st[f], 0, 0, 0);
            }
        }
        __builtin_amdgcn_s_setprio(0);
        // online softmax (base-2), defer-max rescale
        float rm = fmaxf(fmaxf(st[0][0], st[0][1]), fmaxf(st[0][2], st[0][3]));
        rm = fmaxf(rm, fmaxf(fmaxf(st[1][0], st[1][1]), fmaxf(st[1][2], st[1][3])));
        rm = fmaxf(rm, __shfl_xor(rm, 16));
        rm = fmaxf(rm, __shfl_xor(rm, 32));
        if (!__all(rm - mrun <= 8.f)) {
            float mnew = fmaxf(mrun, rm);
            float alpha = exp2f(mrun - mnew);
#pragma unroll
            for (int j = 0; j < 4; ++j) {
                float a4 = __shfl(alpha, (g << 2) + j);
#pragma unroll
                for (int nf = 0; nf < 16; ++nf) acc[nf][j] *= a4;
            }
            mrun = mnew;
            lrun *= alpha;
        }
        float ps = 0.f;
#pragma unroll
        for (int f = 0; f < 2; ++f)
#pragma unroll
            for (int j = 0; j < 4; ++j) { float e = exp2f(st[f][j] - mrun); st[f][j] = e; ps += e; }
        ps += __shfl_xor(ps, 16);
        ps += __shfl_xor(ps, 32);
        lrun += ps;
        s16x8 pa;
        {
            union { s16x8 v; u16 u[8]; } pu;
#pragma unroll
            for (int j2 = 0; j2 < 4; ++j2) { pu.u[j2] = f2b(st[0][j2]); pu.u[4+j2] = f2b(st[1][j2]); }
            pa = pu.v;
        }
        __builtin_amdgcn_s_setprio(1);
#pragma unroll
        for (int nf = 0; nf < 16; ++nf) {
            int row = (nf << 4) + lqi;
            s16x8 bv = *(const s16x8*)(vbuf + ((row << 2) + (g ^ ((row >> 1) & 3))) * 8);
            acc[nf] = __builtin_amdgcn_mfma_f32_16x16x32_bf16(pa, bv, acc[nf], 0, 0, 0);
        }
        __builtin_amdgcn_s_setprio(0);
    };

    STAGE(0, 0);
    for (int t2 = 0; t2 < 64; t2 += 2) {
        __syncthreads();
        STAGE(1, t2 + 1);
        COMPUTE(0);
        __syncthreads();
        if (t2 + 2 < 64) STAGE(0, t2 + 2);
        COMPUTE(1);
    }

    // epilogue
    __syncthreads();
    float linv[4];
#pragma unroll
    for (int j = 0; j < 4; ++j) linv[j] = 1.0f / __shfl(lrun, (g << 2) + j);
    u16* o_lds = smem;   // [64][256] bf16 = 32KB
#pragma unroll
    for (int nf = 0; nf < 16; ++nf)
#pragma unroll
        for (int j = 0; j < 4; ++j)
            o_lds[(wid * 16 + (g << 2) + j) * 256 + (nf << 4) + lqi] = f2b(acc[nf][j] * linv[j]);
    __syncthreads();
    u16* orow = Opart + (size_t)s * NT + (size_t)(b * 4096 + q0) * 256;
#pragma unroll
    for (int r = 0; r < 8; ++r) {
        int o = (r * 256 + tid) * 8, row = o >> 8, col = o & 255;
        *(s16x8*)(orow + (size_t)row * 256 + col) = *(const s16x8*)(o_lds + row * 256 + col);
    }
    if (lane < 16) {
        int grow = b * 4096 + q0 + wid * 16 + lqi;
        ml[s * 32768 + grow]         = mrun;
        ml[s * 32768 + 16384 + grow] = lrun;
    }
}

// ---------------- tail_fused: recomb(2) + LN1 + GEMM1 + relu + GEMM2 + LN2 ----------------
// One block = 64 token rows. Wl bf16. out fp32.
__global__ __launch_bounds__(256) void tail_fused(const u16* __restrict__ Opart, const float* __restrict__ ml,
                                                  const float* __restrict__ x,
                                                  const float* __restrict__ g1, const float* __restrict__ be1,
                                                  const u16* __restrict__ wl, const float* __restrict__ bl,
                                                  const float* __restrict__ g2, const float* __restrict__ be2,
                                                  float* __restrict__ out) {
    __shared__ __align__(16) u16 smem[32768];   // bufA 32KB + bufB 32KB
    u16* bufA = smem;
    u16* bufB = smem + 16384;
    const int tid = threadIdx.x;
    const int wid = tid >> 6, lane = tid & 63, g = lane >> 4, lqi = lane & 15;
    const int m0 = blockIdx.x * 64;

    // ---- head: recomb 2 splits + LN1 -> bufA (bf16, chunk-swizzled) ----
#pragma unroll 1
    for (int r = 0; r < 16; ++r) {
        int rl = wid * 16 + r;
        int row = m0 + rl;
        float m0v = ml[row],         l0 = ml[16384 + row];
        float m1v = ml[32768 + row], l1 = ml[49152 + row];
        float mm = fmaxf(m0v, m1v);
        float a0 = l0 * exp2f(m0v - mm), a1 = l1 * exp2f(m1v - mm);
        float rs = 1.0f / (a0 + a1);
        a0 *= rs; a1 *= rs;
        u16x4 v0 = *(const u16x4*)(Opart + (size_t)row * 256 + lane * 4);
        u16x4 v1 = *(const u16x4*)(Opart + NT + (size_t)row * 256 + lane * 4);
        f32x4 xv = *(const f32x4*)(x + (size_t)row * 256 + lane * 4);
        float sv[4];
#pragma unroll
        for (int i = 0; i < 4; ++i) sv[i] = xv[i] + a0 * b2f(v0[i]) + a1 * b2f(v1[i]);
        float sum = sv[0]+sv[1]+sv[2]+sv[3];
        float sq = sv[0]*sv[0]+sv[1]*sv[1]+sv[2]*sv[2]+sv[3]*sv[3];
#pragma unroll
        for (int d = 1; d < 64; d <<= 1) { sum += __shfl_xor(sum, d); sq += __shfl_xor(sq, d); }
        float mean = sum * (1.f/256.f);
        float rstd = rsqrtf(sq * (1.f/256.f) - mean*mean + 1e-5f);
        int c = lane * 4;
        int addr = rl * 256 + ((((c >> 3) ^ (rl & 7)) << 3)) + (c & 7);
        u16x4 y;
#pragma unroll
        for (int i = 0; i < 4; ++i) y[i] = f2b((sv[i] - mean) * rstd * g1[c + i] + be1[c + i]);
        *(u16x4*)(bufA + addr) = y;
    }
    __syncthreads();

    // ---- GEMM1: h (bufA) . Wl^T + bl, relu -> bufB (swizzled) ----
    {
        f32x4 acc[16];
#pragma unroll
        for (int nf = 0; nf < 16; ++nf) { acc[nf][0]=0.f; acc[nf][1]=0.f; acc[nf][2]=0.f; acc[nf][3]=0.f; }
        int rl = wid * 16 + lqi;
#pragma unroll
        for (int kk = 0; kk < 8; ++kk) {
            s16x8 a = *(const s16x8*)(bufA + rl * 256 + ((((kk << 2) | g) ^ (rl & 7)) << 3));
#pragma unroll
            for (int nf = 0; nf < 16; ++nf) {
                s16x8 b = *(const s16x8*)(wl + (size_t)(nf * 16 + lqi) * 256 + kk * 32 + g * 8);
                acc[nf] = __builtin_amdgcn_mfma_f32_16x16x32_bf16(a, b, acc[nf], 0, 0, 0);
            }
        }
        __syncthreads();   // bufA reads done before bufB writes? (separate buffers, but keep order w/ bufB reuse below)
#pragma unroll
        for (int nf = 0; nf < 16; ++nf) {
            float bb = bl[nf * 16 + lqi];
            int c = nf * 16 + lqi, ch = c >> 3, lo = c & 7;
#pragma unroll
            for (int j = 0; j < 4; ++j) {
                int ml_ = wid * 16 + (g << 2) + j;
                bufB[ml_ * 256 + (((ch ^ (ml_ & 7)) << 3)) + lo] = f2b(fmaxf(acc[nf][j] + bb, 0.f));
            }
        }
    }
    __syncthreads();

    // ---- GEMM2: h1 (bufB) . Wl^T + bl -> bufA (bf16, plain layout) ----
    {
        f32x4 acc[16];
#pragma unroll
        for (int nf = 0; nf < 16; ++nf) { acc[nf][0]=0.f; acc[nf][1]=0.f; acc[nf][2]=0.f; acc[nf][3]=0.f; }
        int rl = wid * 16 + lqi;
#pragma unroll
        for (int kk = 0; kk < 8; ++kk) {
            s16x8 a = *(const s16x8*)(bufB + rl * 256 + ((((kk << 2) | g) ^ (rl & 7)) << 3));
#pragma unroll
            for (int nf = 0; nf < 16; ++nf) {
                s16x8 b = *(const s16x8*)(wl + (size_t)(nf * 16 + lqi) * 256 + kk * 32 + g * 8);
                acc[nf] = __builtin_amdgcn_mfma_f32_16x16x32_bf16(a, b, acc[nf], 0, 0, 0);
            }
        }
        __syncthreads();
#pragma unroll
        for (int nf = 0; nf < 16; ++nf) {
            float bb = bl[nf * 16 + lqi];
#pragma unroll
            for (int j = 0; j < 4; ++j) {
                int ml_ = wid * 16 + (g << 2) + j;
                bufA[ml_ * 256 + nf * 16 + lqi] = f2b(acc[nf][j] + bb);
            }
        }
    }
    __syncthreads();

    // ---- tail: LN2(x + h2) -> out fp32 ----
#pragma unroll 1
    for (int r = 0; r < 16; ++r) {
        int rl = wid * 16 + r;
        int row = m0 + rl;
        u16x4 av = *(const u16x4*)(bufA + rl * 256 + lane * 4);
        f32x4 xv = *(const f32x4*)(x + (size_t)row * 256 + lane * 4);
        float sv[4];
#pragma unroll
        for (int i = 0; i < 4; ++i) sv[i] = xv[i] + b2f(av[i]);
        float sum = sv[0]+sv[1]+sv[2]+sv[3];
        float sq = sv[0]*sv[0]+sv[1]*sv[1]+sv[2]*sv[2]+sv[3]*sv[3];
#pragma unroll
        for (int d = 1; d < 64; d <<= 1) { sum += __shfl_xor(sum, d); sq += __shfl_xor(sq, d); }
        float mean = sum * (1.f/256.f);
        float rstd = rsqrtf(sq * (1.f/256.f) - mean*mean + 1e-5f);
        int c = lane * 4;
        f32x4 y;
#pragma unroll
        for (int i = 0; i < 4; ++i) y[i] = (sv[i] - mean) * rstd * g2[c + i] + be2[c + i];
        *(f32x4*)(out + (size_t)row * 256 + c) = y;
    }
}

extern "C" void kernel_launch(void* const* d_in, const int* in_sizes, int n_in,
                              void* d_out, int out_size, void* d_ws, size_t ws_size,
                              hipStream_t stream) {
    const float* x   = (const float*)d_in[0];
    const float* Wq  = (const float*)d_in[1];
    const float* bq  = (const float*)d_in[2];
    const float* Wk  = (const float*)d_in[3];
    const float* bk  = (const float*)d_in[4];
    const float* Wv  = (const float*)d_in[5];
    const float* bv  = (const float*)d_in[6];
    const float* Wl  = (const float*)d_in[7];
    const float* bl  = (const float*)d_in[8];
    const float* g1  = (const float*)d_in[9];
    const float* be1 = (const float*)d_in[10];
    const float* g2  = (const float*)d_in[11];
    const float* be2 = (const float*)d_in[12];
    float* out = (float*)d_out;

    // ws (u16 units): wqkv+wl [4*65536] ; kb [NT] ; vtb [NT] ; op [2NT] ; ml [2*2*16384] f32
    // total = 262144 + 4NT + 131072*2 u16 = 34.3 MB  (proven ws >= 50.8 MB)
    u16* wqb  = (u16*)d_ws;              // wq, wk, wv, wl contiguous
    u16* wkb  = wqb + 65536;
    u16* wvb  = wkb + 65536;
    u16* wlb  = wvb + 65536;
    u16* kb   = wlb + 65536;
    u16* vtb  = kb + NT;
    u16* op   = vtb + NT;
    float* ml = (float*)(op + (size_t)2 * NT);

    cvt_w4<<<dim3(64, 4), 256, 0, stream>>>(Wq, Wk, Wv, Wl, wqb);

    gemm_kv<<<dim3(256, 4, 2), 256, 0, stream>>>(x, wkb, wvb, bk, bv, kb, vtb);

    flash6<<<dim3(256, 2), 256, 0, stream>>>(x, wqb, bq, kb, vtb, op, ml);

    tail_fused<<<256, 256, 0, stream>>>(op, ml, x, g1, be1, wlb, bl, g2, be2, out);
}